// Round 15
// baseline (302.232 us; speedup 1.0000x reference)
//
#include <hip/hip_runtime.h>
#include <math.h>

namespace {

typedef unsigned short ushort_t;
typedef unsigned int uint_t;
typedef unsigned char uchar_t;
typedef __attribute__((ext_vector_type(4))) float f32x4;
typedef __attribute__((ext_vector_type(2))) long longx2;

constexpr int NBATCH = 16;
constexpr int NCH    = 21;
constexpr int HH     = 41;
constexpr int NP     = HH * HH;       // 1681 pixels
constexpr int IW     = 321;           // input image H=W
constexpr int QS     = 32;            // padded channel stride for P/LOGU/QF
constexpr float EPSV = 1e-5f;

constexpr int NROWS  = 1696;          // M rows per batch
constexpr int KPAD   = 1792;          // M cols (bytes) padded to 56*32
constexpr int ITL    = 27;            // 64-row tiles per batch
constexpr int ITP    = 14;            // tile-pairs per batch (27 -> 14, last dup-masked)
constexpr int NPIX   = NBATCH * NP;             // 26896
constexpr int LOSS_BLOCKS = (NPIX + 255) / 256; // 106
constexpr int RSB_TILES = (NP + 63) / 64;       // 27

constexpr int NTILE  = 27;                      // 64-wide tiles covering 1728 >= NP
constexpr int NPAIRS = NTILE * (NTILE + 1) / 2; // 378 (ti <= tj)

// B-fragment-linear Q storage (fp8): per batch [56 kb][64 lane][2 ct][8 B]
constexpr int QB_BATCH = 56 * 1024;              // 57344 bytes per batch
constexpr int QB_BUF   = NBATCH * QB_BATCH;      // 917504 bytes per buffer
constexpr int RXN = NBATCH * 3 * IW * HH;        // 631728

constexpr float CS_COLOR = 0.06533245f;   // sqrt(log2(e)/338)
constexpr float CS_XY    = 0.12739827f;   // sqrt(0.01125*log2(e))
constexpr float KGC      = 711.111111f;   // exp(-8*d2)=exp2(-KGC*axy)
constexpr float L2E8     = 11.5415603f;   // 8*log2(e)
constexpr float GATE     = 0.138f;        // axy gate ~ d2<=8

// workspace offsets in floats
constexpr size_t OFF_W    = 0;
constexpr size_t OFF_RX   = 13184;
constexpr size_t OFF_COL  = 644928;
constexpr size_t OFF_P    = 752512;
constexpr size_t OFF_LOGU = 1613184;
constexpr size_t OFF_QF   = 2473856;
constexpr size_t OFF_RSG  = 3334528;
constexpr size_t OFF_XY   = 3336256;
constexpr size_t OFF_PART = 3339712;
constexpr size_t OFF_QB   = 3339968;
constexpr size_t OFF_M    = 3798720;

constexpr size_t QB_ZERO_DWORDS = 458752;        // both QB buffers, dwords
constexpr int ZERO4_BLOCKS = (int)(QB_ZERO_DWORDS / 4 / 256); // 448 (exact)
constexpr int INIT_BLOCKS = 9 + ZERO4_BLOCKS;    // weights|xy*7|rsg|zero(x4)

#define GLOAD_LDS16(g, l)                                                              \
  __builtin_amdgcn_global_load_lds((const __attribute__((address_space(1))) uint_t*)(g), \
                                   (__attribute__((address_space(3))) uint_t*)(l), 16, 0, 0)

// LDS byte address (32-bit) for inline-asm ds_read
#define LDSA(p) ((uint_t)(size_t)(__attribute__((address_space(3))) void*)(p))

__device__ __forceinline__ float wave_sum(float v) {
  #pragma unroll
  for (int off = 32; off > 0; off >>= 1) v += __shfl_down(v, off, 64);
  return v;
}

__device__ __forceinline__ uchar_t f32_to_fp8(float f) {
  return (uchar_t)(__builtin_amdgcn_cvt_pk_fp8_f32(f, f, 0, false) & 0xff);
}

// K0 fused: weights (bid 0) | xy (bid 1..7) | rsg separable (bid 8) | QB zero x4 (rest)
__global__ __launch_bounds__(256) void k_init(float* __restrict__ W,
                                              float2* __restrict__ XY,
                                              float* __restrict__ rsg,
                                              uint4* __restrict__ QZ) {
  const int bid = (int)blockIdx.x;
  const int tid = (int)threadIdx.x;
  if (bid == 0) {
    int o = tid;
    if (o >= HH) return;
    const float inv = (float)IW / (float)HH;
    float s = (o + 0.5f) * inv - 0.5f;
    float tot = 0.f;
    for (int i = 0; i < IW; ++i) {
      float x = fabsf(s - (float)i) / inv;
      tot += fmaxf(0.f, 1.f - x);
    }
    float r = 1.f / tot;
    for (int i = 0; i < IW; ++i) {
      float x = fabsf(s - (float)i) / inv;
      W[o * IW + i] = fmaxf(0.f, 1.f - x) * r;
    }
  } else if (bid <= 7) {
    int j = (bid - 1) * 256 + tid;
    if (j < NP)
      XY[j] = make_float2((float)(j % HH) * CS_XY, (float)(j / HH) * CS_XY);
  } else if (bid == 8) {
    // separable Gaussian row-sum: sum_j e^{-8 d2} = Sx[xi]*Sy[yi] - 1 (self term)
    __shared__ float SX[HH];
    if (tid < HH) {
      float s = 0.f;
      for (int x = 0; x < HH; ++x) {
        float d = (float)(tid - x);
        s += __builtin_amdgcn_exp2f(-L2E8 * d * d);
      }
      SX[tid] = s;
    }
    __syncthreads();
    for (int i = tid; i < NP; i += 256) {
      float s = SX[i % HH] * SX[i / HH] - 1.0f;
      rsg[i] = 1.f / sqrtf(s);
    }
  } else {
    size_t t = (size_t)(bid - 9) * 256 + tid;   // 448 blocks x 256 x uint4 = exact
    QZ[t] = make_uint4(0u, 0u, 0u, 0u);
  }
}

// K2a: separable resize, x pass
__global__ void k_resize_x(const float* __restrict__ img, const float* __restrict__ W,
                           float* __restrict__ RX) {
  int t = blockIdx.x * blockDim.x + threadIdx.x;
  if (t >= RXN) return;
  int xo = t % HH;
  int rest = t / HH;
  int y = rest % IW;
  int nc = rest / IW;
  const float inv = (float)IW / (float)HH;
  float sx = (xo + 0.5f) * inv - 0.5f;
  int xlo = max(0, (int)ceilf(sx - inv)), xhi = min(IW - 1, (int)floorf(sx + inv));
  const float* base = img + ((size_t)nc * IW + y) * IW;
  const float* wr = W + xo * IW;
  float a = 0.f;
  for (int ix = xlo; ix <= xhi; ++ix) a += wr[ix] * base[ix];
  RX[t] = a;
}

// K2b+K3 fused: y-pass resize -> COL, and clamped softmax -> P/LOGU/QB.
__global__ void k_resize_y_probs(const float* __restrict__ RX, const float* __restrict__ W,
                                 float* __restrict__ colors,
                                 const float* __restrict__ pred, float* __restrict__ P,
                                 float* __restrict__ LOGU, uchar_t* __restrict__ QB) {
  int t = blockIdx.x * blockDim.x + threadIdx.x;
  if (t >= NPIX) return;
  int nb = t / NP, i = t % NP;

  {
    int yo = i / HH, xo = i % HH;
    const float inv = (float)IW / (float)HH;
    float sy = (yo + 0.5f) * inv - 0.5f;
    int ylo = max(0, (int)ceilf(sy - inv)), yhi = min(IW - 1, (int)floorf(sy + inv));
    const float* wr = W + yo * IW;
    float a0 = 0.f, a1 = 0.f, a2 = 0.f;
    const float* b0 = RX + (size_t)(nb * 3 + 0) * IW * HH + xo;
    const float* b1 = RX + (size_t)(nb * 3 + 1) * IW * HH + xo;
    const float* b2 = RX + (size_t)(nb * 3 + 2) * IW * HH + xo;
    for (int iy = ylo; iy <= yhi; ++iy) {
      float wy = wr[iy];
      a0 += wy * b0[(size_t)iy * HH];
      a1 += wy * b1[(size_t)iy * HH];
      a2 += wy * b2[(size_t)iy * HH];
    }
    float* c = colors + (size_t)t * 4;
    c[0] = a0 * CS_COLOR; c[1] = a1 * CS_COLOR; c[2] = a2 * CS_COLOR; c[3] = 0.f;
  }

  {
    const float* src = pred + (size_t)nb * NCH * NP + i;
    float v[NCH];
    float m = -1e30f;
    #pragma unroll
    for (int c = 0; c < NCH; ++c) { v[c] = src[(size_t)c * NP]; m = fmaxf(m, v[c]); }
    float s = 0.f;
    #pragma unroll
    for (int c = 0; c < NCH; ++c) { v[c] = expf(v[c] - m); s += v[c]; }
    float r = 1.f / s;
    float s2 = 0.f;
    #pragma unroll
    for (int c = 0; c < NCH; ++c) { v[c] = fminf(fmaxf(v[c] * r, EPSV), 1.0f); s2 += v[c]; }
    float r2 = 1.f / s2;
    float* dp = P + (size_t)t * QS;
    float* dl = LOGU + (size_t)t * QS;
    int kb = i >> 5, kr = i & 31, q2 = kr >> 3, j = kr & 7;
    size_t sb = (size_t)nb * QB_BATCH + (size_t)kb * 1024 + j;
    #pragma unroll
    for (int c = 0; c < NCH; ++c) {
      float p = v[c] * r2;
      dp[c] = p; dl[c] = logf(p);
      QB[sb + (size_t)(q2 * 16 + (c & 15)) * 16 + (size_t)(c >> 4) * 8] = f32_to_fp8(p);
    }
  }
}

// K5: bilateral row sums -> colors.w (LDS-tiled)
__global__ __launch_bounds__(512) void k_rsb(float4* __restrict__ COL,
                                             const float2* __restrict__ XY) {
  __shared__ float S8[NP * 8];
  __shared__ float Red2[8 * 64];
  const int nb = blockIdx.x / RSB_TILES;
  const int i0 = (blockIdx.x % RSB_TILES) * 64;
  const int tid = (int)threadIdx.x;
  const int lane = tid & 63, wv = tid >> 6;

  const float4* colb = COL + (size_t)nb * NP;
  for (int j = tid; j < NP; j += 512) {
    float4 c = colb[j];
    float2 xy = XY[j];
    *(float4*)&S8[j * 8]     = make_float4(c.x, c.y, c.z, 0.f);
    *(float4*)&S8[j * 8 + 4] = make_float4(xy.x, xy.y, 0.f, 0.f);
  }
  __syncthreads();

  const int i = i0 + lane;
  const int im = min(i, NP - 1);
  const float ci0 = S8[im * 8], ci1 = S8[im * 8 + 1], ci2 = S8[im * 8 + 2];
  const float xi = S8[im * 8 + 4], yi = S8[im * 8 + 5];

  float s = 0.f;
  for (int j = wv; j < NP; j += 8) {
    float4 a = *(const float4*)&S8[j * 8];
    float4 b = *(const float4*)&S8[j * 8 + 4];
    float dx = xi - b.x, dy = yi - b.y;
    float acc = dx * dx;
    acc = fmaf(dy, dy, acc);
    float e0 = ci0 - a.x, e1 = ci1 - a.y, e2 = ci2 - a.z;
    acc = fmaf(e0, e0, acc);
    acc = fmaf(e1, e1, acc);
    acc = fmaf(e2, e2, acc);
    s += __builtin_amdgcn_exp2f(-acc);
  }
  Red2[wv * 64 + lane] = s;
  __syncthreads();
  if (wv == 0 && i < NP) {
    float t = -1.0f;
    #pragma unroll
    for (int w = 0; w < 8; ++w) t += Red2[w * 64 + lane];
    ((float*)(COL + (size_t)nb * NP + i))[3] = 1.f / sqrtf(t);
  }
}

// K6: symmetric 64x64-tile build (round-2 proven).
__global__ __launch_bounds__(256) void k_buildM(const float4* __restrict__ COL,
                                                const float* __restrict__ rsg,
                                                uchar_t* __restrict__ M) {
  __shared__ float4 CI[64], CJ[64];
  __shared__ float RI[64], RJ[64];
  __shared__ uint_t Tt[64 * 21];

  const int nb = blockIdx.x & 15;
  int p = blockIdx.x >> 4;
  int ti = 0;
  while (p >= NTILE - ti) { p -= NTILE - ti; ++ti; }
  const int tj = ti + p;
  const int i0 = ti * 64, j0 = tj * 64;
  const int tid = (int)threadIdx.x;

  const float4* colb = COL + (size_t)nb * NP;
  if (tid < 64) {
    int g = min(i0 + tid, NP - 1);
    CI[tid] = colb[g];
    RI[tid] = rsg[g];
  } else if (tid < 128) {
    int t = tid - 64;
    int g = min(j0 + t, NP - 1);
    CJ[t] = colb[g];
    RJ[t] = rsg[g];
  }
  __syncthreads();

  const int r4 = tid >> 4;
  const int c4 = tid & 15;
  const int ii0 = r4 * 4, jj0 = c4 * 4;

  float xi[4], yi[4], ci0a[4], ci1a[4], ci2a[4], sbi[4], sgi[4];
  #pragma unroll
  for (int e = 0; e < 4; ++e) {
    int gi = i0 + ii0 + e;
    xi[e] = (float)(gi % HH) * CS_XY;
    yi[e] = (float)(gi / HH) * CS_XY;
    float4 c = CI[ii0 + e];
    ci0a[e] = c.x; ci1a[e] = c.y; ci2a[e] = c.z;
    sbi[e] = 10.f * c.w;
    sgi[e] = 3.f * RI[ii0 + e];
  }
  float xj[4], yj[4], cj0a[4], cj1a[4], cj2a[4], wj[4], rj[4];
  #pragma unroll
  for (int e = 0; e < 4; ++e) {
    int gj = j0 + jj0 + e;
    xj[e] = (float)(gj % HH) * CS_XY;
    yj[e] = (float)(gj / HH) * CS_XY;
    float4 c = CJ[jj0 + e];
    cj0a[e] = c.x; cj1a[e] = c.y; cj2a[e] = c.z;
    wj[e] = c.w; rj[e] = RJ[jj0 + e];
  }

  float v[4][4];
  #pragma unroll
  for (int i = 0; i < 4; ++i) {
    int gi = i0 + ii0 + i;
    #pragma unroll
    for (int j = 0; j < 4; ++j) {
      int gj = j0 + jj0 + j;
      float dx = xi[i] - xj[j], dy = yi[i] - yj[j];
      float axy = fmaf(dy, dy, dx * dx);
      float e0 = ci0a[i] - cj0a[j], e1 = ci1a[i] - cj1a[j], e2 = ci2a[i] - cj2a[j];
      float acc = axy;
      acc = fmaf(e0, e0, acc);
      acc = fmaf(e1, e1, acc);
      acc = fmaf(e2, e2, acc);
      float val = __builtin_amdgcn_exp2f(-acc) * sbi[i] * wj[j];
      if (axy < GATE) val = fmaf(__builtin_amdgcn_exp2f(-KGC * axy), sgi[i] * rj[j], val);
      if (gj >= NP || gj == gi) val = 0.f;
      v[i][j] = val;
    }
  }

  const size_t mbase = (size_t)nb * NROWS * KPAD;

  #pragma unroll
  for (int i = 0; i < 4; ++i) {
    uint_t wrd = __builtin_amdgcn_cvt_pk_fp8_f32(v[i][0], v[i][1], 0, false);
    wrd = __builtin_amdgcn_cvt_pk_fp8_f32(v[i][2], v[i][3], (int)wrd, true);
    int gi = i0 + ii0 + i;
    if (gi < NP)
      ((uint_t*)(M + mbase + (size_t)gi * KPAD))[(j0 >> 2) + c4] = wrd;
  }

  if (ti != tj) {
    #pragma unroll
    for (int j = 0; j < 4; ++j) {
      uint_t wrd = __builtin_amdgcn_cvt_pk_fp8_f32(v[0][j], v[1][j], 0, false);
      wrd = __builtin_amdgcn_cvt_pk_fp8_f32(v[2][j], v[3][j], (int)wrd, true);
      Tt[(jj0 + j) * 21 + r4] = wrd;
    }
    __syncthreads();
    int jj = tid >> 2, sg = tid & 3;
    uint_t o0 = Tt[jj * 21 + sg * 4 + 0];
    uint_t o1 = Tt[jj * 21 + sg * 4 + 1];
    uint_t o2 = Tt[jj * 21 + sg * 4 + 2];
    uint_t o3 = Tt[jj * 21 + sg * 4 + 3];
    int gj = j0 + jj;
    if (gj < NP) {
      uint4 ov = make_uint4(o0, o1, o2, o3);
      *(uint4*)(((uint_t*)(M + mbase + (size_t)gj * KPAD)) + (i0 >> 2) + sg * 4) = ov;
    }
  }
}

// K7 v13 (resubmit — R14 bench was an infra failure, no data): 512 threads =
// 2 independent tile-groups per workgroup (grid 224). Discriminating
// experiment: halves WORKGROUP count at constant per-CU staged bytes.
// k_iter-family dispatches measured ~45 ns/WG (R5 432wg/19us; R10 216wg/
// 10.4us-iter) vs buildM ~4.6 ns/WG (6048wg/28us) — difference is LDS/WG.
// If the floor is per-WG fixed cost, this halves it; if it's per-CU
// staged-byte throughput, this is null and both remaining theories are
// exhausted. Group g = tid>>8 runs the R5-proven 4-wave pipeline on tile
// (pair*2+g). Tile 27 (pair 13, g=1) duplicates tile 26 with ALL writes
// suppressed so barrier participation stays symmetric.
__global__ __launch_bounds__(512) void k_iter(const uchar_t* __restrict__ M,
                                              const uchar_t* __restrict__ QBin,
                                              uchar_t* __restrict__ QBout,
                                              const float* __restrict__ LOGU,
                                              float* __restrict__ QF, int last) {
  __shared__ __align__(16) uchar_t Abuf[2][2][64 * 256];   // [group][buf] 2x32 KB
  __shared__ __align__(16) uchar_t Bbuf[2][2][8 * 1024];   // [group][buf] 2x16 KB
  const int nb = blockIdx.x & 15;
  const int pair = blockIdx.x >> 4;        // 0..13
  const int tid = (int)threadIdx.x;
  const int g = tid >> 8;                  // tile-group 0/1
  const int lt = tid & 255;
  const int lane = lt & 63;
  const int w = lt >> 6;                   // 0..3 within group
  const int mrow = lane & 15, quad = lane >> 4;

  const int tileIdx = pair * 2 + g;        // 0..27
  const bool dup = (tileIdx >= ITL);       // tile 27 -> recompute tile 26, no writes
  const int t0 = (dup ? (ITL - 1) : tileIdx) * 64;

  f32x4 acc0 = {0.f, 0.f, 0.f, 0.f};    // ch 0..15
  f32x4 acc1 = {0.f, 0.f, 0.f, 0.f};    // ch 16..20

  const size_t Mrow0 = (size_t)(nb * NROWS + t0);
  const uchar_t* Qb = QBin + (size_t)nb * QB_BATCH;

  const uint_t abase0 = LDSA(&Abuf[g][0][0]) + (uint_t)((w * 16 + mrow) * 256 + (quad & 1) * 8);
  const uint_t abase1 = LDSA(&Abuf[g][1][0]) + (uint_t)((w * 16 + mrow) * 256 + (quad & 1) * 8);
  const uint_t bbase0 = LDSA(&Bbuf[g][0][0]) + (uint_t)(lane * 16);
  const uint_t bbase1 = LDSA(&Bbuf[g][1][0]) + (uint_t)(lane * 16);
  const int mx = mrow & 7;

  #define STAGE(kc, bf)                                                              \
    do {                                                                             \
      _Pragma("unroll")                                                              \
      for (int t4 = 0; t4 < 4; ++t4) {                                               \
        int t = w * 4 + t4;                                                          \
        int r = t * 4 + (lane >> 4);                                                 \
        int ug = (lane & 15) ^ (r & 7);                                              \
        GLOAD_LDS16(M + (Mrow0 + r) * KPAD + (kc) * 256 + ug * 16,                   \
                    &Abuf[g][bf][t * 1024]);                                         \
      }                                                                              \
      _Pragma("unroll")                                                              \
      for (int t2 = 0; t2 < 2; ++t2) {                                               \
        int t = w * 2 + t2;                                                          \
        GLOAD_LDS16(Qb + (size_t)(kc) * 8192 + t * 1024 + lane * 16,                 \
                    &Bbuf[g][bf][t * 1024]);                                         \
      }                                                                              \
    } while (0)

  #define COMPUTE(ab, bb)                                                            \
    do {                                                                             \
      long a_c, a_n;                                                                 \
      longx2 b_c, b_n;                                                               \
      asm volatile("ds_read_b64 %0, %1" : "=v"(a_c)                                  \
                   : "v"((ab) + (uint_t)((((quad >> 1)) ^ mx) * 16)));               \
      asm volatile("ds_read_b128 %0, %1" : "=v"(b_c) : "v"(bb));                     \
      _Pragma("unroll")                                                              \
      for (int c = 0; c < 8; ++c) {                                                  \
        if (c < 7) {                                                                 \
          asm volatile("ds_read_b64 %0, %1" : "=v"(a_n)                              \
                       : "v"((ab) + (uint_t)((((c + 1) * 2 + (quad >> 1)) ^ mx) * 16))); \
          asm volatile("ds_read_b128 %0, %1" : "=v"(b_n)                             \
                       : "v"((bb) + (uint_t)((c + 1) * 1024)));                      \
          asm volatile("s_waitcnt lgkmcnt(2)" ::: "memory");                         \
        } else {                                                                     \
          asm volatile("s_waitcnt lgkmcnt(0)" ::: "memory");                         \
        }                                                                            \
        __builtin_amdgcn_sched_barrier(0);                                           \
        acc0 = __builtin_amdgcn_mfma_f32_16x16x32_fp8_fp8(a_c, b_c[0], acc0, 0, 0, 0); \
        acc1 = __builtin_amdgcn_mfma_f32_16x16x32_fp8_fp8(a_c, b_c[1], acc1, 0, 0, 0); \
        a_c = a_n; b_c = b_n;                                                        \
      }                                                                              \
    } while (0)

  #define VMBAR()                                                                    \
    do {                                                                             \
      asm volatile("s_waitcnt vmcnt(0)" ::: "memory");                               \
      __builtin_amdgcn_s_barrier();                                                  \
      __builtin_amdgcn_sched_barrier(0);                                             \
    } while (0)

  STAGE(0, 0);
  VMBAR();
  #pragma unroll
  for (int kc = 0; kc < 7; ++kc) {
    if (kc < 6) {
      if (kc & 1) STAGE(kc + 1, 0); else STAGE(kc + 1, 1);
    }
    if (kc & 1) COMPUTE(abase1, bbase1); else COMPUTE(abase0, bbase0);
    if (kc < 6) VMBAR();
  }

  #undef STAGE
  #undef COMPUTE
  #undef VMBAR

  const bool c1ok = (mrow + 16) < NCH;
  #pragma unroll
  for (int reg = 0; reg < 4; ++reg) {
    int r = t0 + w * 16 + quad * 4 + reg;
    int rg = nb * NP + min(r, NP - 1);
    float tv0 = LOGU[(size_t)rg * QS + mrow] + acc0[reg];
    float tv1 = c1ok ? (LOGU[(size_t)rg * QS + 16 + mrow] + acc1[reg]) : -1e30f;
    float mx2 = fmaxf(tv0, tv1);
    mx2 = fmaxf(mx2, __shfl_xor(mx2, 1));
    mx2 = fmaxf(mx2, __shfl_xor(mx2, 2));
    mx2 = fmaxf(mx2, __shfl_xor(mx2, 4));
    mx2 = fmaxf(mx2, __shfl_xor(mx2, 8));
    float e0 = __expf(tv0 - mx2);
    float e1 = c1ok ? __expf(tv1 - mx2) : 0.f;
    float sm = e0 + e1;
    sm += __shfl_xor(sm, 1);
    sm += __shfl_xor(sm, 2);
    sm += __shfl_xor(sm, 4);
    sm += __shfl_xor(sm, 8);
    float rinv = 1.f / sm;
    if (r < NP && !dup) {
      int kb = r >> 5, kr = r & 31, q2 = kr >> 3, j = kr & 7;
      size_t sbo = (size_t)nb * QB_BATCH + (size_t)kb * 1024 +
                   (size_t)(q2 * 16 + mrow) * 16 + j;
      float q0 = e0 * rinv;
      QBout[sbo] = f32_to_fp8(q0);
      if (last) QF[(size_t)(nb * NP + r) * QS + mrow] = q0;
      if (c1ok) {
        float q1 = e1 * rinv;
        QBout[sbo + 8] = f32_to_fp8(q1);
        if (last) QF[(size_t)(nb * NP + r) * QS + 16 + mrow] = q1;
      }
    }
  }
}

// K8: per-pixel loss contribution
__global__ void k_loss(const float* __restrict__ Qf, const float* __restrict__ P,
                       float* __restrict__ part) {
  int t = blockIdx.x * blockDim.x + threadIdx.x;
  float s = 0.f;
  if (t < NPIX) {
    const float* q = Qf + (size_t)t * QS;
    const float* p = P + (size_t)t * QS;
    float qv[NCH];
    float qsum = 0.f;
    #pragma unroll
    for (int c = 0; c < NCH; ++c) { qv[c] = fmaxf(q[c], EPSV); qsum += qv[c]; }
    float r = 1.f / qsum;
    #pragma unroll
    for (int c = 0; c < NCH; ++c) {
      float qs = qv[c] * r;
      float ratio = fminf(fmaxf(qs / p[c], 0.05f), 20.0f);
      s += qs * logf(ratio);
    }
  }
  __shared__ float red[256];
  red[threadIdx.x] = s;
  __syncthreads();
  for (int st = 128; st > 0; st >>= 1) {
    if ((int)threadIdx.x < st) red[threadIdx.x] += red[threadIdx.x + st];
    __syncthreads();
  }
  if (threadIdx.x == 0) part[blockIdx.x] = red[0];
}

// K9: final reduction -> d_out[0]
__global__ void k_final(const float* __restrict__ part, float* __restrict__ out) {
  float s = 0.f;
  for (int k = threadIdx.x; k < LOSS_BLOCKS; k += 64) s += part[k];
  s = wave_sum(s);
  if (threadIdx.x == 0) out[0] = s / (float)NPIX;
}

}  // namespace

extern "C" void kernel_launch(void* const* d_in, const int* in_sizes, int n_in,
                              void* d_out, int out_size, void* d_ws, size_t ws_size,
                              hipStream_t stream) {
  const float* images  = (const float*)d_in[0];   // (16,3,321,321) fp32
  const float* predict = (const float*)d_in[1];   // (16,21,41,41) fp32
  float* out = (float*)d_out;
  float* ws = (float*)d_ws;

  float*  W    = ws + OFF_W;
  float*  RX   = ws + OFF_RX;
  float4* COL  = (float4*)(ws + OFF_COL);
  float*  P    = ws + OFF_P;
  float*  LOGU = ws + OFF_LOGU;
  float*  QF   = ws + OFF_QF;
  float*  RSG  = ws + OFF_RSG;
  float2* XY   = (float2*)(ws + OFF_XY);
  float*  PART = ws + OFF_PART;
  uchar_t* QB_A = (uchar_t*)(ws + OFF_QB);
  uchar_t* QB_B = QB_A + (size_t)QB_BUF;
  uchar_t* M    = (uchar_t*)(ws + OFF_M);

  hipLaunchKernelGGL(k_init, dim3(INIT_BLOCKS), dim3(256), 0, stream,
                     W, XY, RSG, (uint4*)QB_A);
  hipLaunchKernelGGL(k_resize_x, dim3((RXN + 255) / 256), dim3(256), 0, stream, images, W, RX);
  hipLaunchKernelGGL(k_resize_y_probs, dim3(LOSS_BLOCKS), dim3(256), 0, stream,
                     RX, W, (float*)COL, predict, P, LOGU, QB_A);
  hipLaunchKernelGGL(k_rsb, dim3(NBATCH * RSB_TILES), dim3(512), 0, stream, COL, XY);
  hipLaunchKernelGGL(k_buildM, dim3(NBATCH * NPAIRS), dim3(256), 0, stream, COL, RSG, M);

  const uchar_t* qbin = QB_A;
  uchar_t* qbout = QB_B;
  for (int it = 0; it < 10; ++it) {
    hipLaunchKernelGGL(k_iter, dim3(NBATCH * ITP), dim3(512), 0, stream,
                       M, qbin, qbout, LOGU, QF, (it == 9) ? 1 : 0);
    const uchar_t* t = qbout; qbout = (uchar_t*)qbin; qbin = t;
  }
  hipLaunchKernelGGL(k_loss, dim3(LOSS_BLOCKS), dim3(256), 0, stream, QF, P, PART);
  hipLaunchKernelGGL(k_final, dim3(1), dim3(64), 0, stream, PART, out);
}

// Round 16
// 287.079 us; speedup vs baseline: 1.0528x; 1.0528x over previous
//
#include <hip/hip_runtime.h>
#include <math.h>

namespace {

typedef unsigned short ushort_t;
typedef unsigned int uint_t;
typedef unsigned char uchar_t;
typedef __attribute__((ext_vector_type(4))) float f32x4;
typedef __attribute__((ext_vector_type(2))) long longx2;

constexpr int NBATCH = 16;
constexpr int NCH    = 21;
constexpr int HH     = 41;
constexpr int NP     = HH * HH;       // 1681 pixels
constexpr int IW     = 321;           // input image H=W
constexpr int QS     = 32;            // padded channel stride for P/LOGU/QF
constexpr float EPSV = 1e-5f;

constexpr int NROWS  = 1696;          // M rows per batch
constexpr int KPAD   = 1792;          // M cols (bytes) padded to 56*32
constexpr int ITL    = 27;            // 64-row tiles per batch
constexpr int NPIX   = NBATCH * NP;             // 26896
constexpr int LOSS_BLOCKS = (NPIX + 255) / 256; // 106
constexpr int RSB_TILES = (NP + 63) / 64;       // 27

constexpr int NTILE  = 27;                      // 64-wide tiles covering 1728 >= NP
constexpr int NPAIRS = NTILE * (NTILE + 1) / 2; // 378 (ti <= tj)

// B-fragment-linear Q storage (fp8): per batch [56 kb][64 lane][2 ct][8 B]
constexpr int QB_BATCH = 56 * 1024;              // 57344 bytes per batch
constexpr int QB_BUF   = NBATCH * QB_BATCH;      // 917504 bytes per buffer
constexpr int RXN = NBATCH * 3 * IW * HH;        // 631728

constexpr float CS_COLOR = 0.06533245f;   // sqrt(log2(e)/338)
constexpr float CS_XY    = 0.12739827f;   // sqrt(0.01125*log2(e))
constexpr float KGC      = 711.111111f;   // exp(-8*d2)=exp2(-KGC*axy)
constexpr float L2E8     = 11.5415603f;   // 8*log2(e)
constexpr float GATE     = 0.138f;        // axy gate ~ d2<=8

// workspace offsets in floats
constexpr size_t OFF_W    = 0;
constexpr size_t OFF_RX   = 13184;
constexpr size_t OFF_COL  = 644928;
constexpr size_t OFF_P    = 752512;
constexpr size_t OFF_LOGU = 1613184;
constexpr size_t OFF_QF   = 2473856;
constexpr size_t OFF_RSG  = 3334528;
constexpr size_t OFF_XY   = 3336256;
constexpr size_t OFF_PART = 3339712;
constexpr size_t OFF_QB   = 3339968;
constexpr size_t OFF_M    = 3798720;

constexpr size_t QB_ZERO_DWORDS = 458752;        // both QB buffers, dwords
constexpr int ZERO4_BLOCKS = (int)(QB_ZERO_DWORDS / 4 / 256); // 448 (exact)
constexpr int INIT_BLOCKS = 9 + ZERO4_BLOCKS;    // weights|xy*7|rsg|zero(x4)

#define GLOAD_LDS16(g, l)                                                              \
  __builtin_amdgcn_global_load_lds((const __attribute__((address_space(1))) uint_t*)(g), \
                                   (__attribute__((address_space(3))) uint_t*)(l), 16, 0, 0)

// LDS byte address (32-bit) for inline-asm ds_read
#define LDSA(p) ((uint_t)(size_t)(__attribute__((address_space(3))) void*)(p))

__device__ __forceinline__ float wave_sum(float v) {
  #pragma unroll
  for (int off = 32; off > 0; off >>= 1) v += __shfl_down(v, off, 64);
  return v;
}

__device__ __forceinline__ uchar_t f32_to_fp8(float f) {
  return (uchar_t)(__builtin_amdgcn_cvt_pk_fp8_f32(f, f, 0, false) & 0xff);
}

// K0 fused: weights (bid 0) | xy (bid 1..7) | rsg separable (bid 8) | QB zero x4 (rest)
__global__ __launch_bounds__(256) void k_init(float* __restrict__ W,
                                              float2* __restrict__ XY,
                                              float* __restrict__ rsg,
                                              uint4* __restrict__ QZ) {
  const int bid = (int)blockIdx.x;
  const int tid = (int)threadIdx.x;
  if (bid == 0) {
    int o = tid;
    if (o >= HH) return;
    const float inv = (float)IW / (float)HH;
    float s = (o + 0.5f) * inv - 0.5f;
    float tot = 0.f;
    for (int i = 0; i < IW; ++i) {
      float x = fabsf(s - (float)i) / inv;
      tot += fmaxf(0.f, 1.f - x);
    }
    float r = 1.f / tot;
    for (int i = 0; i < IW; ++i) {
      float x = fabsf(s - (float)i) / inv;
      W[o * IW + i] = fmaxf(0.f, 1.f - x) * r;
    }
  } else if (bid <= 7) {
    int j = (bid - 1) * 256 + tid;
    if (j < NP)
      XY[j] = make_float2((float)(j % HH) * CS_XY, (float)(j / HH) * CS_XY);
  } else if (bid == 8) {
    // separable Gaussian row-sum: sum_j e^{-8 d2} = Sx[xi]*Sy[yi] - 1 (self term)
    __shared__ float SX[HH];
    if (tid < HH) {
      float s = 0.f;
      for (int x = 0; x < HH; ++x) {
        float d = (float)(tid - x);
        s += __builtin_amdgcn_exp2f(-L2E8 * d * d);
      }
      SX[tid] = s;
    }
    __syncthreads();
    for (int i = tid; i < NP; i += 256) {
      float s = SX[i % HH] * SX[i / HH] - 1.0f;
      rsg[i] = 1.f / sqrtf(s);
    }
  } else {
    size_t t = (size_t)(bid - 9) * 256 + tid;   // 448 blocks x 256 x uint4 = exact
    QZ[t] = make_uint4(0u, 0u, 0u, 0u);
  }
}

// K2a: separable resize, x pass
__global__ void k_resize_x(const float* __restrict__ img, const float* __restrict__ W,
                           float* __restrict__ RX) {
  int t = blockIdx.x * blockDim.x + threadIdx.x;
  if (t >= RXN) return;
  int xo = t % HH;
  int rest = t / HH;
  int y = rest % IW;
  int nc = rest / IW;
  const float inv = (float)IW / (float)HH;
  float sx = (xo + 0.5f) * inv - 0.5f;
  int xlo = max(0, (int)ceilf(sx - inv)), xhi = min(IW - 1, (int)floorf(sx + inv));
  const float* base = img + ((size_t)nc * IW + y) * IW;
  const float* wr = W + xo * IW;
  float a = 0.f;
  for (int ix = xlo; ix <= xhi; ++ix) a += wr[ix] * base[ix];
  RX[t] = a;
}

// K2b+K3 fused: y-pass resize -> COL, and clamped softmax -> P/LOGU/QB.
__global__ void k_resize_y_probs(const float* __restrict__ RX, const float* __restrict__ W,
                                 float* __restrict__ colors,
                                 const float* __restrict__ pred, float* __restrict__ P,
                                 float* __restrict__ LOGU, uchar_t* __restrict__ QB) {
  int t = blockIdx.x * blockDim.x + threadIdx.x;
  if (t >= NPIX) return;
  int nb = t / NP, i = t % NP;

  {
    int yo = i / HH, xo = i % HH;
    const float inv = (float)IW / (float)HH;
    float sy = (yo + 0.5f) * inv - 0.5f;
    int ylo = max(0, (int)ceilf(sy - inv)), yhi = min(IW - 1, (int)floorf(sy + inv));
    const float* wr = W + yo * IW;
    float a0 = 0.f, a1 = 0.f, a2 = 0.f;
    const float* b0 = RX + (size_t)(nb * 3 + 0) * IW * HH + xo;
    const float* b1 = RX + (size_t)(nb * 3 + 1) * IW * HH + xo;
    const float* b2 = RX + (size_t)(nb * 3 + 2) * IW * HH + xo;
    for (int iy = ylo; iy <= yhi; ++iy) {
      float wy = wr[iy];
      a0 += wy * b0[(size_t)iy * HH];
      a1 += wy * b1[(size_t)iy * HH];
      a2 += wy * b2[(size_t)iy * HH];
    }
    float* c = colors + (size_t)t * 4;
    c[0] = a0 * CS_COLOR; c[1] = a1 * CS_COLOR; c[2] = a2 * CS_COLOR; c[3] = 0.f;
  }

  {
    const float* src = pred + (size_t)nb * NCH * NP + i;
    float v[NCH];
    float m = -1e30f;
    #pragma unroll
    for (int c = 0; c < NCH; ++c) { v[c] = src[(size_t)c * NP]; m = fmaxf(m, v[c]); }
    float s = 0.f;
    #pragma unroll
    for (int c = 0; c < NCH; ++c) { v[c] = expf(v[c] - m); s += v[c]; }
    float r = 1.f / s;
    float s2 = 0.f;
    #pragma unroll
    for (int c = 0; c < NCH; ++c) { v[c] = fminf(fmaxf(v[c] * r, EPSV), 1.0f); s2 += v[c]; }
    float r2 = 1.f / s2;
    float* dp = P + (size_t)t * QS;
    float* dl = LOGU + (size_t)t * QS;
    int kb = i >> 5, kr = i & 31, q2 = kr >> 3, j = kr & 7;
    size_t sb = (size_t)nb * QB_BATCH + (size_t)kb * 1024 + j;
    #pragma unroll
    for (int c = 0; c < NCH; ++c) {
      float p = v[c] * r2;
      dp[c] = p; dl[c] = logf(p);
      QB[sb + (size_t)(q2 * 16 + (c & 15)) * 16 + (size_t)(c >> 4) * 8] = f32_to_fp8(p);
    }
  }
}

// K5: bilateral row sums -> colors.w (LDS-tiled)
__global__ __launch_bounds__(512) void k_rsb(float4* __restrict__ COL,
                                             const float2* __restrict__ XY) {
  __shared__ float S8[NP * 8];
  __shared__ float Red2[8 * 64];
  const int nb = blockIdx.x / RSB_TILES;
  const int i0 = (blockIdx.x % RSB_TILES) * 64;
  const int tid = (int)threadIdx.x;
  const int lane = tid & 63, wv = tid >> 6;

  const float4* colb = COL + (size_t)nb * NP;
  for (int j = tid; j < NP; j += 512) {
    float4 c = colb[j];
    float2 xy = XY[j];
    *(float4*)&S8[j * 8]     = make_float4(c.x, c.y, c.z, 0.f);
    *(float4*)&S8[j * 8 + 4] = make_float4(xy.x, xy.y, 0.f, 0.f);
  }
  __syncthreads();

  const int i = i0 + lane;
  const int im = min(i, NP - 1);
  const float ci0 = S8[im * 8], ci1 = S8[im * 8 + 1], ci2 = S8[im * 8 + 2];
  const float xi = S8[im * 8 + 4], yi = S8[im * 8 + 5];

  float s = 0.f;
  for (int j = wv; j < NP; j += 8) {
    float4 a = *(const float4*)&S8[j * 8];
    float4 b = *(const float4*)&S8[j * 8 + 4];
    float dx = xi - b.x, dy = yi - b.y;
    float acc = dx * dx;
    acc = fmaf(dy, dy, acc);
    float e0 = ci0 - a.x, e1 = ci1 - a.y, e2 = ci2 - a.z;
    acc = fmaf(e0, e0, acc);
    acc = fmaf(e1, e1, acc);
    acc = fmaf(e2, e2, acc);
    s += __builtin_amdgcn_exp2f(-acc);
  }
  Red2[wv * 64 + lane] = s;
  __syncthreads();
  if (wv == 0 && i < NP) {
    float t = -1.0f;
    #pragma unroll
    for (int w = 0; w < 8; ++w) t += Red2[w * 64 + lane];
    ((float*)(COL + (size_t)nb * NP + i))[3] = 1.f / sqrtf(t);
  }
}

// K6: symmetric 64x64-tile build (round-2 proven).
__global__ __launch_bounds__(256) void k_buildM(const float4* __restrict__ COL,
                                                const float* __restrict__ rsg,
                                                uchar_t* __restrict__ M) {
  __shared__ float4 CI[64], CJ[64];
  __shared__ float RI[64], RJ[64];
  __shared__ uint_t Tt[64 * 21];

  const int nb = blockIdx.x & 15;
  int p = blockIdx.x >> 4;
  int ti = 0;
  while (p >= NTILE - ti) { p -= NTILE - ti; ++ti; }
  const int tj = ti + p;
  const int i0 = ti * 64, j0 = tj * 64;
  const int tid = (int)threadIdx.x;

  const float4* colb = COL + (size_t)nb * NP;
  if (tid < 64) {
    int g = min(i0 + tid, NP - 1);
    CI[tid] = colb[g];
    RI[tid] = rsg[g];
  } else if (tid < 128) {
    int t = tid - 64;
    int g = min(j0 + t, NP - 1);
    CJ[t] = colb[g];
    RJ[t] = rsg[g];
  }
  __syncthreads();

  const int r4 = tid >> 4;
  const int c4 = tid & 15;
  const int ii0 = r4 * 4, jj0 = c4 * 4;

  float xi[4], yi[4], ci0a[4], ci1a[4], ci2a[4], sbi[4], sgi[4];
  #pragma unroll
  for (int e = 0; e < 4; ++e) {
    int gi = i0 + ii0 + e;
    xi[e] = (float)(gi % HH) * CS_XY;
    yi[e] = (float)(gi / HH) * CS_XY;
    float4 c = CI[ii0 + e];
    ci0a[e] = c.x; ci1a[e] = c.y; ci2a[e] = c.z;
    sbi[e] = 10.f * c.w;
    sgi[e] = 3.f * RI[ii0 + e];
  }
  float xj[4], yj[4], cj0a[4], cj1a[4], cj2a[4], wj[4], rj[4];
  #pragma unroll
  for (int e = 0; e < 4; ++e) {
    int gj = j0 + jj0 + e;
    xj[e] = (float)(gj % HH) * CS_XY;
    yj[e] = (float)(gj / HH) * CS_XY;
    float4 c = CJ[jj0 + e];
    cj0a[e] = c.x; cj1a[e] = c.y; cj2a[e] = c.z;
    wj[e] = c.w; rj[e] = RJ[jj0 + e];
  }

  float v[4][4];
  #pragma unroll
  for (int i = 0; i < 4; ++i) {
    int gi = i0 + ii0 + i;
    #pragma unroll
    for (int j = 0; j < 4; ++j) {
      int gj = j0 + jj0 + j;
      float dx = xi[i] - xj[j], dy = yi[i] - yj[j];
      float axy = fmaf(dy, dy, dx * dx);
      float e0 = ci0a[i] - cj0a[j], e1 = ci1a[i] - cj1a[j], e2 = ci2a[i] - cj2a[j];
      float acc = axy;
      acc = fmaf(e0, e0, acc);
      acc = fmaf(e1, e1, acc);
      acc = fmaf(e2, e2, acc);
      float val = __builtin_amdgcn_exp2f(-acc) * sbi[i] * wj[j];
      if (axy < GATE) val = fmaf(__builtin_amdgcn_exp2f(-KGC * axy), sgi[i] * rj[j], val);
      if (gj >= NP || gj == gi) val = 0.f;
      v[i][j] = val;
    }
  }

  const size_t mbase = (size_t)nb * NROWS * KPAD;

  #pragma unroll
  for (int i = 0; i < 4; ++i) {
    uint_t wrd = __builtin_amdgcn_cvt_pk_fp8_f32(v[i][0], v[i][1], 0, false);
    wrd = __builtin_amdgcn_cvt_pk_fp8_f32(v[i][2], v[i][3], (int)wrd, true);
    int gi = i0 + ii0 + i;
    if (gi < NP)
      ((uint_t*)(M + mbase + (size_t)gi * KPAD))[(j0 >> 2) + c4] = wrd;
  }

  if (ti != tj) {
    #pragma unroll
    for (int j = 0; j < 4; ++j) {
      uint_t wrd = __builtin_amdgcn_cvt_pk_fp8_f32(v[0][j], v[1][j], 0, false);
      wrd = __builtin_amdgcn_cvt_pk_fp8_f32(v[2][j], v[3][j], (int)wrd, true);
      Tt[(jj0 + j) * 21 + r4] = wrd;
    }
    __syncthreads();
    int jj = tid >> 2, sg = tid & 3;
    uint_t o0 = Tt[jj * 21 + sg * 4 + 0];
    uint_t o1 = Tt[jj * 21 + sg * 4 + 1];
    uint_t o2 = Tt[jj * 21 + sg * 4 + 2];
    uint_t o3 = Tt[jj * 21 + sg * 4 + 3];
    int gj = j0 + jj;
    if (gj < NP) {
      uint4 ov = make_uint4(o0, o1, o2, o3);
      *(uint4*)(((uint_t*)(M + mbase + (size_t)gj * KPAD)) + (i0 >> 2) + sg * 4) = ov;
    }
  }
}

// K7: R5-exact (best measured configuration, 288.2 us total). 2-phase asm
// pipeline: STAGE(next) -> COMPUTE(cur) via inline-asm ds_read + counted
// lgkmcnt -> vmcnt(0)+barrier once per K-tile. 15 rounds of restructuring
// (schedule/barriers/paths/partition/persistence/WG-count) all measured at
// or worse than this — the per-dispatch latency+overhead floor.
__global__ __launch_bounds__(256) void k_iter(const uchar_t* __restrict__ M,
                                              const uchar_t* __restrict__ QBin,
                                              uchar_t* __restrict__ QBout,
                                              const float* __restrict__ LOGU,
                                              float* __restrict__ QF, int last) {
  __shared__ __align__(16) uchar_t Abuf[2][64 * 256];   // 2 x 16 KB
  __shared__ __align__(16) uchar_t Bbuf[2][8 * 1024];   // 2 x 8 KB
  const int nb = blockIdx.x & 15;
  const int t0 = (blockIdx.x >> 4) * 64;
  const int tid = (int)threadIdx.x;
  const int lane = tid & 63;
  const int w = tid >> 6;               // 0..3
  const int mrow = lane & 15, quad = lane >> 4;

  f32x4 acc0 = {0.f, 0.f, 0.f, 0.f};    // ch 0..15
  f32x4 acc1 = {0.f, 0.f, 0.f, 0.f};    // ch 16..20

  const size_t Mrow0 = (size_t)(nb * NROWS + t0);
  const uchar_t* Qb = QBin + (size_t)nb * QB_BATCH;

  const uint_t abase0 = LDSA(&Abuf[0][0]) + (uint_t)((w * 16 + mrow) * 256 + (quad & 1) * 8);
  const uint_t abase1 = LDSA(&Abuf[1][0]) + (uint_t)((w * 16 + mrow) * 256 + (quad & 1) * 8);
  const uint_t bbase0 = LDSA(&Bbuf[0][0]) + (uint_t)(lane * 16);
  const uint_t bbase1 = LDSA(&Bbuf[1][0]) + (uint_t)(lane * 16);
  const int mx = mrow & 7;

  #define STAGE(kc, bf)                                                              \
    do {                                                                             \
      _Pragma("unroll")                                                              \
      for (int t4 = 0; t4 < 4; ++t4) {                                               \
        int t = w * 4 + t4;                                                          \
        int r = t * 4 + (lane >> 4);                                                 \
        int ug = (lane & 15) ^ (r & 7);                                              \
        GLOAD_LDS16(M + (Mrow0 + r) * KPAD + (kc) * 256 + ug * 16,                   \
                    &Abuf[bf][t * 1024]);                                            \
      }                                                                              \
      _Pragma("unroll")                                                              \
      for (int t2 = 0; t2 < 2; ++t2) {                                               \
        int t = w * 2 + t2;                                                          \
        GLOAD_LDS16(Qb + (size_t)(kc) * 8192 + t * 1024 + lane * 16,                 \
                    &Bbuf[bf][t * 1024]);                                            \
      }                                                                              \
    } while (0)

  #define COMPUTE(ab, bb)                                                            \
    do {                                                                             \
      long a_c, a_n;                                                                 \
      longx2 b_c, b_n;                                                               \
      asm volatile("ds_read_b64 %0, %1" : "=v"(a_c)                                  \
                   : "v"((ab) + (uint_t)((((quad >> 1)) ^ mx) * 16)));               \
      asm volatile("ds_read_b128 %0, %1" : "=v"(b_c) : "v"(bb));                     \
      _Pragma("unroll")                                                              \
      for (int c = 0; c < 8; ++c) {                                                  \
        if (c < 7) {                                                                 \
          asm volatile("ds_read_b64 %0, %1" : "=v"(a_n)                              \
                       : "v"((ab) + (uint_t)((((c + 1) * 2 + (quad >> 1)) ^ mx) * 16))); \
          asm volatile("ds_read_b128 %0, %1" : "=v"(b_n)                             \
                       : "v"((bb) + (uint_t)((c + 1) * 1024)));                      \
          asm volatile("s_waitcnt lgkmcnt(2)" ::: "memory");                         \
        } else {                                                                     \
          asm volatile("s_waitcnt lgkmcnt(0)" ::: "memory");                         \
        }                                                                            \
        __builtin_amdgcn_sched_barrier(0);                                           \
        acc0 = __builtin_amdgcn_mfma_f32_16x16x32_fp8_fp8(a_c, b_c[0], acc0, 0, 0, 0); \
        acc1 = __builtin_amdgcn_mfma_f32_16x16x32_fp8_fp8(a_c, b_c[1], acc1, 0, 0, 0); \
        a_c = a_n; b_c = b_n;                                                        \
      }                                                                              \
    } while (0)

  #define VMBAR()                                                                    \
    do {                                                                             \
      asm volatile("s_waitcnt vmcnt(0)" ::: "memory");                               \
      __builtin_amdgcn_s_barrier();                                                  \
      __builtin_amdgcn_sched_barrier(0);                                             \
    } while (0)

  STAGE(0, 0);
  VMBAR();
  #pragma unroll
  for (int kc = 0; kc < 7; ++kc) {
    if (kc < 6) {
      if (kc & 1) STAGE(kc + 1, 0); else STAGE(kc + 1, 1);
    }
    if (kc & 1) COMPUTE(abase1, bbase1); else COMPUTE(abase0, bbase0);
    if (kc < 6) VMBAR();
  }

  #undef STAGE
  #undef COMPUTE
  #undef VMBAR

  const bool c1ok = (mrow + 16) < NCH;
  #pragma unroll
  for (int reg = 0; reg < 4; ++reg) {
    int r = t0 + w * 16 + quad * 4 + reg;
    int rg = nb * NP + min(r, NP - 1);
    float tv0 = LOGU[(size_t)rg * QS + mrow] + acc0[reg];
    float tv1 = c1ok ? (LOGU[(size_t)rg * QS + 16 + mrow] + acc1[reg]) : -1e30f;
    float mx2 = fmaxf(tv0, tv1);
    mx2 = fmaxf(mx2, __shfl_xor(mx2, 1));
    mx2 = fmaxf(mx2, __shfl_xor(mx2, 2));
    mx2 = fmaxf(mx2, __shfl_xor(mx2, 4));
    mx2 = fmaxf(mx2, __shfl_xor(mx2, 8));
    float e0 = __expf(tv0 - mx2);
    float e1 = c1ok ? __expf(tv1 - mx2) : 0.f;
    float sm = e0 + e1;
    sm += __shfl_xor(sm, 1);
    sm += __shfl_xor(sm, 2);
    sm += __shfl_xor(sm, 4);
    sm += __shfl_xor(sm, 8);
    float rinv = 1.f / sm;
    if (r < NP) {
      int kb = r >> 5, kr = r & 31, q2 = kr >> 3, j = kr & 7;
      size_t sbo = (size_t)nb * QB_BATCH + (size_t)kb * 1024 +
                   (size_t)(q2 * 16 + mrow) * 16 + j;
      float q0 = e0 * rinv;
      QBout[sbo] = f32_to_fp8(q0);
      if (last) QF[(size_t)(nb * NP + r) * QS + mrow] = q0;
      if (c1ok) {
        float q1 = e1 * rinv;
        QBout[sbo + 8] = f32_to_fp8(q1);
        if (last) QF[(size_t)(nb * NP + r) * QS + 16 + mrow] = q1;
      }
    }
  }
}

// K8: per-pixel loss contribution
__global__ void k_loss(const float* __restrict__ Qf, const float* __restrict__ P,
                       float* __restrict__ part) {
  int t = blockIdx.x * blockDim.x + threadIdx.x;
  float s = 0.f;
  if (t < NPIX) {
    const float* q = Qf + (size_t)t * QS;
    const float* p = P + (size_t)t * QS;
    float qv[NCH];
    float qsum = 0.f;
    #pragma unroll
    for (int c = 0; c < NCH; ++c) { qv[c] = fmaxf(q[c], EPSV); qsum += qv[c]; }
    float r = 1.f / qsum;
    #pragma unroll
    for (int c = 0; c < NCH; ++c) {
      float qs = qv[c] * r;
      float ratio = fminf(fmaxf(qs / p[c], 0.05f), 20.0f);
      s += qs * logf(ratio);
    }
  }
  __shared__ float red[256];
  red[threadIdx.x] = s;
  __syncthreads();
  for (int st = 128; st > 0; st >>= 1) {
    if ((int)threadIdx.x < st) red[threadIdx.x] += red[threadIdx.x + st];
    __syncthreads();
  }
  if (threadIdx.x == 0) part[blockIdx.x] = red[0];
}

// K9: final reduction -> d_out[0]
__global__ void k_final(const float* __restrict__ part, float* __restrict__ out) {
  float s = 0.f;
  for (int k = threadIdx.x; k < LOSS_BLOCKS; k += 64) s += part[k];
  s = wave_sum(s);
  if (threadIdx.x == 0) out[0] = s / (float)NPIX;
}

}  // namespace

extern "C" void kernel_launch(void* const* d_in, const int* in_sizes, int n_in,
                              void* d_out, int out_size, void* d_ws, size_t ws_size,
                              hipStream_t stream) {
  const float* images  = (const float*)d_in[0];   // (16,3,321,321) fp32
  const float* predict = (const float*)d_in[1];   // (16,21,41,41) fp32
  float* out = (float*)d_out;
  float* ws = (float*)d_ws;

  float*  W    = ws + OFF_W;
  float*  RX   = ws + OFF_RX;
  float4* COL  = (float4*)(ws + OFF_COL);
  float*  P    = ws + OFF_P;
  float*  LOGU = ws + OFF_LOGU;
  float*  QF   = ws + OFF_QF;
  float*  RSG  = ws + OFF_RSG;
  float2* XY   = (float2*)(ws + OFF_XY);
  float*  PART = ws + OFF_PART;
  uchar_t* QB_A = (uchar_t*)(ws + OFF_QB);
  uchar_t* QB_B = QB_A + (size_t)QB_BUF;
  uchar_t* M    = (uchar_t*)(ws + OFF_M);

  hipLaunchKernelGGL(k_init, dim3(INIT_BLOCKS), dim3(256), 0, stream,
                     W, XY, RSG, (uint4*)QB_A);
  hipLaunchKernelGGL(k_resize_x, dim3((RXN + 255) / 256), dim3(256), 0, stream, images, W, RX);
  hipLaunchKernelGGL(k_resize_y_probs, dim3(LOSS_BLOCKS), dim3(256), 0, stream,
                     RX, W, (float*)COL, predict, P, LOGU, QB_A);
  hipLaunchKernelGGL(k_rsb, dim3(NBATCH * RSB_TILES), dim3(512), 0, stream, COL, XY);
  hipLaunchKernelGGL(k_buildM, dim3(NBATCH * NPAIRS), dim3(256), 0, stream, COL, RSG, M);

  const uchar_t* qbin = QB_A;
  uchar_t* qbout = QB_B;
  for (int it = 0; it < 10; ++it) {
    hipLaunchKernelGGL(k_iter, dim3(NBATCH * ITL), dim3(256), 0, stream,
                       M, qbin, qbout, LOGU, QF, (it == 9) ? 1 : 0);
    const uchar_t* t = qbout; qbout = (uchar_t*)qbin; qbin = t;
  }
  hipLaunchKernelGGL(k_loss, dim3(LOSS_BLOCKS), dim3(256), 0, stream, QF, P, PART);
  hipLaunchKernelGGL(k_final, dim3(1), dim3(64), 0, stream, PART, out);
}